// Round 1
// baseline (89.743 us; speedup 1.0000x reference)
//
#include <hip/hip_runtime.h>

// SparseMatmul3D: out[b,n,m] = sum_k x[b,n,k] * y[b,m,k]
// B=4, N=M=4096, D=64, fp32 in/out. Write-bound (268 MB out).
// Strategy: bf16 MFMA (16x16x32), transposed product so each lane stores
// 4 contiguous fp32 (dwordx4), no LDS (K=64, inputs L2-resident).

#define BATCH 4
#define NN 4096
#define MM 4096
#define DD 64

typedef __attribute__((ext_vector_type(8))) short bf16x8;
typedef __attribute__((ext_vector_type(4))) float f32x4;

__device__ __forceinline__ unsigned short f2bf(float f) {
    unsigned u = __builtin_bit_cast(unsigned, f);
    u += 0x7FFFu + ((u >> 16) & 1u);   // round-to-nearest-even
    return (unsigned short)(u >> 16);
}

__device__ __forceinline__ bf16x8 load8_bf16(const float* __restrict__ p) {
    f32x4 v0 = *reinterpret_cast<const f32x4*>(p);
    f32x4 v1 = *reinterpret_cast<const f32x4*>(p + 4);
    bf16x8 r;
    r[0] = (short)f2bf(v0[0]); r[1] = (short)f2bf(v0[1]);
    r[2] = (short)f2bf(v0[2]); r[3] = (short)f2bf(v0[3]);
    r[4] = (short)f2bf(v1[0]); r[5] = (short)f2bf(v1[1]);
    r[6] = (short)f2bf(v1[2]); r[7] = (short)f2bf(v1[3]);
    return r;
}

__global__ __launch_bounds__(256) void
SparseMatmul3D_36155034698289_kernel(const float* __restrict__ x,
                                     const float* __restrict__ y,
                                     float* __restrict__ out) {
    const int b    = blockIdx.z;
    const int m0   = blockIdx.x * 128;   // m tile base
    const int n0   = blockIdx.y * 128;   // n tile base
    const int lane = threadIdx.x & 63;
    const int w    = threadIdx.x >> 6;   // wave 0..3
    const int wm   = (w >> 1) * 64;      // wave m offset
    const int wn   = (w & 1) * 64;       // wave n offset

    const int row16 = lane & 15;         // fragment row/col index
    const int kgrp  = lane >> 4;         // 0..3 -> k chunk of 8

    const float* __restrict__ xb = x + (size_t)b * NN * DD;
    const float* __restrict__ yb = y + (size_t)b * MM * DD;

    // A = y-tile (i = m), B = x-tile (j = n)  =>  D[i][j] = out[n0+j][m0+i]
    bf16x8 afrag[4][2];  // [m-subtile][k-step]
    bf16x8 bfrag[4][2];  // [n-subtile][k-step]

#pragma unroll
    for (int mt = 0; mt < 4; ++mt) {
        const float* p = yb + (size_t)(m0 + wm + mt * 16 + row16) * DD + kgrp * 8;
        afrag[mt][0] = load8_bf16(p);
        afrag[mt][1] = load8_bf16(p + 32);
    }
#pragma unroll
    for (int nt = 0; nt < 4; ++nt) {
        const float* p = xb + (size_t)(n0 + wn + nt * 16 + row16) * DD + kgrp * 8;
        bfrag[nt][0] = load8_bf16(p);
        bfrag[nt][1] = load8_bf16(p + 32);
    }

    f32x4 acc[4][4];
#pragma unroll
    for (int mt = 0; mt < 4; ++mt)
#pragma unroll
        for (int nt = 0; nt < 4; ++nt)
            acc[mt][nt] = (f32x4){0.f, 0.f, 0.f, 0.f};

#pragma unroll
    for (int ks = 0; ks < 2; ++ks)
#pragma unroll
        for (int mt = 0; mt < 4; ++mt)
#pragma unroll
            for (int nt = 0; nt < 4; ++nt)
                acc[mt][nt] = __builtin_amdgcn_mfma_f32_16x16x32_bf16(
                    afrag[mt][ks], bfrag[nt][ks], acc[mt][nt], 0, 0, 0);

    // C/D layout (16x16): col = lane&15 (=j=n), row = (lane>>4)*4 + reg (=i=m)
    // => each lane stores 4 consecutive m at fixed n: contiguous dwordx4.
    float* __restrict__ ob = out + (size_t)b * NN * MM;
#pragma unroll
    for (int nt = 0; nt < 4; ++nt) {
        const int n = n0 + wn + nt * 16 + row16;
        float* orow = ob + (size_t)n * MM;
#pragma unroll
        for (int mt = 0; mt < 4; ++mt) {
            const int m = m0 + wm + mt * 16 + kgrp * 4;
            *reinterpret_cast<f32x4*>(orow + m) = acc[mt][nt];
        }
    }
}

extern "C" void kernel_launch(void* const* d_in, const int* in_sizes, int n_in,
                              void* d_out, int out_size, void* d_ws, size_t ws_size,
                              hipStream_t stream) {
    const float* x = (const float*)d_in[0];
    const float* y = (const float*)d_in[1];
    float* out = (float*)d_out;

    dim3 grid(MM / 128, NN / 128, BATCH);
    dim3 block(256);
    SparseMatmul3D_36155034698289_kernel<<<grid, block, 0, stream>>>(x, y, out);
}